// Round 1
// baseline (330.715 us; speedup 1.0000x reference)
//
#include <hip/hip_runtime.h>

// Problem constants (from reference setup_inputs):
//   B=4 batches, A=160000 anchors, G=64 gt boxes
//   inputs: anchors [B,A,4] f32, gt_boxes [B,G,4] f32,
//           score_labels [B,G] f32, confidence_labels [B,G] i32
//   outputs (concat flat): labels [B,A] f32, matched_gt_boxes [B,A,4] f32
constexpr int NB = 4;
constexpr int NA = 160000;
constexpr int NG = 64;

// --- exact-rounding helpers -------------------------------------------------
// Must be bit-identical to the numpy fp32 reference:
//  - contract(off): stop the compiler fusing (s - w*h) into fma, which would
//    change rounding vs numpy's separate mul+sub.
//  - plain '/' is IEEE-correct fp32 on hipcc without -ffast-math.

__device__ __forceinline__ float box_area(float x0, float y0, float x1, float y1) {
#pragma clang fp contract(off)
    return (x1 - x0) * (y1 - y0);
}

__device__ __forceinline__ float iou_f(float gx0, float gy0, float gx1, float gy1, float garea,
                                       float ax0, float ay0, float ax1, float ay1, float aarea) {
#pragma clang fp contract(off)
    float ltx = fmaxf(gx0, ax0);
    float lty = fmaxf(gy0, ay0);
    float rbx = fminf(gx1, ax1);
    float rby = fminf(gy1, ay1);
    float w = fmaxf(rbx - ltx, 0.0f);
    float h = fmaxf(rby - lty, 0.0f);
    float inter = w * h;
    float s = garea + aarea;        // numpy: area_a[:,None] + area_b[None,:]
    float denom = s - inter;        // then  - inter
    return inter / denom;           // IEEE fp32 divide
}

// --- kernel 1: highest IoU per gt (max over all anchors) --------------------
// grid (125, B), block 256; each thread owns 5 anchors (125*256*5 == 160000).
__global__ __launch_bounds__(256) void k_gt_highest(
        const float* __restrict__ anchors, const float* __restrict__ gts,
        float* __restrict__ highest /* [B*G], pre-zeroed */) {
    const int b = blockIdx.y;
    const int t = blockIdx.x * 256 + threadIdx.x;   // 0..31999
    const float4* __restrict__ anc = reinterpret_cast<const float4*>(anchors) + (size_t)b * NA;
    const float4* __restrict__ gt  = reinterpret_cast<const float4*>(gts) + b * NG;

    float4 a[5];
    float aarea[5];
#pragma unroll
    for (int i = 0; i < 5; ++i) {
        a[i] = anc[t + i * 32000];                  // coalesced, stride 32000
        aarea[i] = box_area(a[i].x, a[i].y, a[i].z, a[i].w);
    }

    const int lane = threadIdx.x & 63;
    for (int g = 0; g < NG; ++g) {
        float4 gb = gt[g];                          // uniform -> scalar load
        float garea = box_area(gb.x, gb.y, gb.z, gb.w);
        float m = 0.0f;
#pragma unroll
        for (int i = 0; i < 5; ++i) {
            float v = iou_f(gb.x, gb.y, gb.z, gb.w, garea,
                            a[i].x, a[i].y, a[i].z, a[i].w, aarea[i]);
            m = fmaxf(m, v);
        }
        // wave64 max-reduce; IoU >= 0 so float order == int order of bits
        for (int off = 32; off > 0; off >>= 1)
            m = fmaxf(m, __shfl_down(m, off));
        if (lane == 0)
            atomicMax(reinterpret_cast<int*>(&highest[b * NG + g]), __float_as_int(m));
    }
}

// --- kernel 2: per-anchor match + labels + matched boxes --------------------
// grid (625, B), block 256; one thread per anchor (625*256 == 160000).
__global__ __launch_bounds__(256) void k_assign(
        const float* __restrict__ anchors, const float* __restrict__ gts,
        const float* __restrict__ scores, const int* __restrict__ confs,
        const float* __restrict__ highest,
        float* __restrict__ labels_out, float4* __restrict__ boxes_out) {
    const int b = blockIdx.y;
    const int ai = blockIdx.x * 256 + threadIdx.x;  // 0..159999
    const float4* __restrict__ anc = reinterpret_cast<const float4*>(anchors) + (size_t)b * NA;
    const float4* __restrict__ gt  = reinterpret_cast<const float4*>(gts) + b * NG;
    const float* __restrict__ hi   = highest + b * NG;

    float4 av = anc[ai];
    float aarea = box_area(av.x, av.y, av.z, av.w);

    float best = -1.0f;     // so all-zero row gives argmax 0 (first max)
    int   matches = 0;
    bool  lowq = false;
    for (int g = 0; g < NG; ++g) {
        float4 gb = gt[g];                          // uniform -> scalar load
        float garea = box_area(gb.x, gb.y, gb.z, gb.w);
        float v = iou_f(gb.x, gb.y, gb.z, gb.w, garea,
                        av.x, av.y, av.z, av.w, aarea);
        if (v > best) { best = v; matches = g; }    // strict > keeps FIRST max
        lowq |= (v == hi[g]);                       // bit-exact equality
    }

    int m    = (best < 0.3f) ? -1 : ((best < 0.7f) ? -2 : matches);
    int midx = lowq ? matches : m;
    int cl   = (midx < 0) ? 0 : midx;

    float4 mg = gt[cl];
    float  sc = scores[b * NG + cl];
    int    cf = confs[b * NG + cl];

    bool pos = (midx >= 0);
    float lab = pos ? 1.0f : 0.0f;
    lab = fminf(lab, sc);
    if (midx == -1) lab = 0.0f;
    if (midx == -2) lab = -1.0f;
    if (sc < 1.0f && pos) lab = -1.0f;
    if (cf == 0 && pos) lab = -1.0f;

    labels_out[(size_t)b * NA + ai] = lab;
    boxes_out[(size_t)b * NA + ai] = mg;            // aligned: 640000 f32 offset
}

extern "C" void kernel_launch(void* const* d_in, const int* in_sizes, int n_in,
                              void* d_out, int out_size, void* d_ws, size_t ws_size,
                              hipStream_t stream) {
    const float* anchors = (const float*)d_in[0];   // [B,A,4]
    const float* gts     = (const float*)d_in[1];   // [B,G,4]
    const float* scores  = (const float*)d_in[2];   // [B,G]
    const int*   confs   = (const int*)d_in[3];     // [B,G]

    float* labels_out = (float*)d_out;                          // [B,A]
    float4* boxes_out = (float4*)((float*)d_out + (size_t)NB * NA); // [B,A,4]
    float* highest = (float*)d_ws;                              // [B*G]

    // zero the per-gt running max (ws is poisoned 0xAA each call)
    hipMemsetAsync(d_ws, 0, (size_t)NB * NG * sizeof(float), stream);

    dim3 g1(125, NB), g2(625, NB), blk(256);
    k_gt_highest<<<g1, blk, 0, stream>>>(anchors, gts, highest);
    k_assign<<<g2, blk, 0, stream>>>(anchors, gts, scores, confs, highest,
                                     labels_out, boxes_out);
}

// Round 2
// 153.330 us; speedup vs baseline: 2.1569x; 2.1569x over previous
//
#include <hip/hip_runtime.h>

// Problem: B=4, A=160000 anchors, G=64 gt boxes.
// outputs (concat flat): labels [B,A] f32, matched_gt_boxes [B,A,4] f32
constexpr int NB = 4;
constexpr int NA = 160000;
constexpr int NG = 64;

// --- exact-rounding helpers (byte-identical to the round-1 passing kernel) --
__device__ __forceinline__ float box_area(float x0, float y0, float x1, float y1) {
#pragma clang fp contract(off)
    return (x1 - x0) * (y1 - y0);
}

__device__ __forceinline__ float iou_f(float gx0, float gy0, float gx1, float gy1, float garea,
                                       float ax0, float ay0, float ax1, float ay1, float aarea) {
#pragma clang fp contract(off)
    float ltx = fmaxf(gx0, ax0);
    float lty = fmaxf(gy0, ay0);
    float rbx = fminf(gx1, ax1);
    float rby = fminf(gy1, ay1);
    float w = fmaxf(rbx - ltx, 0.0f);
    float h = fmaxf(rby - lty, 0.0f);
    float inter = w * h;
    float s = garea + aarea;        // numpy: area_gt + area_anchor
    float denom = s - inter;
    return inter / denom;           // IEEE fp32 divide
}

// --- kernel 1: highest IoU per gt, TRANSPOSED lane mapping ------------------
// grid (250, NB), block 256 (4 waves). Wave w of block handles anchors
// [blockIdx.x*640 + w*160, +160). Lane g holds the running max for gt g:
// anchor coords are wave-uniform (scalar loads), NO shuffles, NO in-loop
// atomics. Block-reduce 4 waves via LDS, one 64-lane atomicMax per block.
__global__ __launch_bounds__(256) void k_gt_highest(
        const float* __restrict__ anchors, const float* __restrict__ gts,
        float* __restrict__ highest /* [B*G], pre-zeroed */) {
    const int b = blockIdx.y;
    const int lane = threadIdx.x & 63;
    const int wid = __builtin_amdgcn_readfirstlane(threadIdx.x >> 6);

    const float4* __restrict__ gt4 = reinterpret_cast<const float4*>(gts) + b * NG;
    const float4* __restrict__ anc = reinterpret_cast<const float4*>(anchors) + (size_t)b * NA;

    // lane g owns gt g (coalesced float4 load, lives in registers all kernel)
    float4 g = gt4[lane];
    float garea = box_area(g.x, g.y, g.z, g.w);

    const int base = blockIdx.x * 640 + wid * 160;
    float acc = 0.0f;
#pragma unroll 8
    for (int i = 0; i < 160; ++i) {
        float4 a = anc[base + i];               // wave-uniform -> scalar load
        float aarea = box_area(a.x, a.y, a.z, a.w);
        float v = iou_f(g.x, g.y, g.z, g.w, garea,
                        a.x, a.y, a.z, a.w, aarea);
        acc = fmaxf(acc, v);
    }

    __shared__ float part[4][NG];
    part[wid][lane] = acc;
    __syncthreads();
    if (threadIdx.x < NG) {
        float m = fmaxf(fmaxf(part[0][threadIdx.x], part[1][threadIdx.x]),
                        fmaxf(part[2][threadIdx.x], part[3][threadIdx.x]));
        // IoU >= 0: float order == int order of bits
        atomicMax(reinterpret_cast<int*>(&highest[b * NG + threadIdx.x]),
                  __float_as_int(m));
    }
}

// --- kernel 2: per-anchor match + labels + matched boxes --------------------
// grid (625, NB), block 256; one thread per anchor. All per-gt data staged in
// LDS once, 64-gt loop fully unrolled (immediate LDS offsets, independent
// divides for ILP).
__global__ __launch_bounds__(256) void k_assign(
        const float* __restrict__ anchors, const float* __restrict__ gts,
        const float* __restrict__ scores, const int* __restrict__ confs,
        const float* __restrict__ highest,
        float* __restrict__ labels_out, float4* __restrict__ boxes_out) {
    __shared__ float4 sg[NG];
    __shared__ float sga[NG], shi[NG], ssc[NG];
    __shared__ int scf[NG];

    const int b = blockIdx.y;
    if (threadIdx.x < NG) {
        const int gi = threadIdx.x;
        float4 gv = reinterpret_cast<const float4*>(gts)[b * NG + gi];
        sg[gi] = gv;
        sga[gi] = box_area(gv.x, gv.y, gv.z, gv.w);
        shi[gi] = highest[b * NG + gi];
        ssc[gi] = scores[b * NG + gi];
        scf[gi] = confs[b * NG + gi];
    }
    __syncthreads();

    const int ai = blockIdx.x * 256 + threadIdx.x;  // 0..159999
    const float4* __restrict__ anc = reinterpret_cast<const float4*>(anchors) + (size_t)b * NA;
    float4 av = anc[ai];
    float aarea = box_area(av.x, av.y, av.z, av.w);

    float best = -1.0f;     // all-zero row -> argmax 0 (first max)
    int   matches = 0;
    bool  lowq = false;
#pragma unroll
    for (int g = 0; g < NG; ++g) {
        float4 gb = sg[g];                          // LDS broadcast
        float v = iou_f(gb.x, gb.y, gb.z, gb.w, sga[g],
                        av.x, av.y, av.z, av.w, aarea);
        if (v > best) { best = v; matches = g; }    // strict > keeps FIRST max
        lowq |= (v == shi[g]);                      // bit-exact equality
    }

    int m    = (best < 0.3f) ? -1 : ((best < 0.7f) ? -2 : matches);
    int midx = lowq ? matches : m;
    int cl   = (midx < 0) ? 0 : midx;

    float4 mg = sg[cl];
    float  sc = ssc[cl];
    int    cf = scf[cl];

    bool pos = (midx >= 0);
    float lab = pos ? 1.0f : 0.0f;
    lab = fminf(lab, sc);
    if (midx == -1) lab = 0.0f;
    if (midx == -2) lab = -1.0f;
    if (sc < 1.0f && pos) lab = -1.0f;
    if (cf == 0 && pos) lab = -1.0f;

    labels_out[(size_t)b * NA + ai] = lab;
    boxes_out[(size_t)b * NA + ai] = mg;
}

extern "C" void kernel_launch(void* const* d_in, const int* in_sizes, int n_in,
                              void* d_out, int out_size, void* d_ws, size_t ws_size,
                              hipStream_t stream) {
    const float* anchors = (const float*)d_in[0];   // [B,A,4]
    const float* gts     = (const float*)d_in[1];   // [B,G,4]
    const float* scores  = (const float*)d_in[2];   // [B,G]
    const int*   confs   = (const int*)d_in[3];     // [B,G]

    float* labels_out = (float*)d_out;                              // [B,A]
    float4* boxes_out = (float4*)((float*)d_out + (size_t)NB * NA); // [B,A,4]
    float* highest = (float*)d_ws;                                  // [B*G]

    hipMemsetAsync(d_ws, 0, (size_t)NB * NG * sizeof(float), stream);

    dim3 g1(250, NB), g2(625, NB), blk(256);
    k_gt_highest<<<g1, blk, 0, stream>>>(anchors, gts, highest);
    k_assign<<<g2, blk, 0, stream>>>(anchors, gts, scores, confs, highest,
                                     labels_out, boxes_out);
}

// Round 3
// 146.637 us; speedup vs baseline: 2.2553x; 1.0456x over previous
//
#include <hip/hip_runtime.h>

// Problem: B=4, A=160000 anchors, G=64 gt boxes.
// outputs (concat flat): labels [B,A] f32, matched_gt_boxes [B,A,4] f32
constexpr int NB = 4;
constexpr int NA = 160000;
constexpr int NG = 64;

// --- exact-rounding helpers -------------------------------------------------
// contract(off): stop fma fusion that would change rounding vs numpy.
__device__ __forceinline__ float box_area(float x0, float y0, float x1, float y1) {
#pragma clang fp contract(off)
    return (x1 - x0) * (y1 - y0);
}

// inter/denom with the exact op order of the numpy reference; shared by both
// kernels so phase-1's deferred quotient is bit-identical to phase-2's.
__device__ __forceinline__ void inter_denom(float gx0, float gy0, float gx1, float gy1, float garea,
                                            float ax0, float ay0, float ax1, float ay1, float aarea,
                                            float& inter, float& denom) {
#pragma clang fp contract(off)
    float ltx = fmaxf(gx0, ax0);
    float lty = fmaxf(gy0, ay0);
    float rbx = fminf(gx1, ax1);
    float rby = fminf(gy1, ay1);
    float w = fmaxf(rbx - ltx, 0.0f);
    float h = fmaxf(rby - lty, 0.0f);
    inter = w * h;
    float s = garea + aarea;        // numpy: area_gt + area_anchor
    denom = s - inter;
}

__device__ __forceinline__ float iou_f(float gx0, float gy0, float gx1, float gy1, float garea,
                                       float ax0, float ay0, float ax1, float ay1, float aarea) {
    float inter, denom;
    inter_denom(gx0, gy0, gx1, gy1, garea, ax0, ay0, ax1, ay1, aarea, inter, denom);
    return inter / denom;           // IEEE fp32 divide
}

// exact comparison  i1/d1 > i2/d2  (all >= 0, d > 0): f64 products of fp32
// are exact (24x24 bits <= 53), so this is the REAL-number ordering. Rounding
// is monotone, so the real-max pair's fp32 quotient == max of rounded quotients.
__device__ __forceinline__ bool frac_gt(float i1, float d1, float i2, float d2) {
    return (double)i1 * (double)d2 > (double)i2 * (double)d1;
}

// --- kernel 1: highest IoU per gt, transposed lanes, divide-free loop -------
// grid (1000, NB), block 256 (4 waves); wave handles 40 anchors. Lane g keeps
// the running-max (inter,denom) pair for gt g; anchors stream as wave-uniform
// scalar loads. One divide per gt per block at the end.
__global__ __launch_bounds__(256) void k_gt_highest(
        const float* __restrict__ anchors, const float* __restrict__ gts,
        float* __restrict__ highest /* [B*G], pre-zeroed */) {
    const int b = blockIdx.y;
    const int lane = threadIdx.x & 63;
    const int wid = __builtin_amdgcn_readfirstlane(threadIdx.x >> 6);

    const float4* __restrict__ gt4 = reinterpret_cast<const float4*>(gts) + b * NG;
    const float4* __restrict__ anc = reinterpret_cast<const float4*>(anchors) + (size_t)b * NA;

    float4 g = gt4[lane];
    float garea = box_area(g.x, g.y, g.z, g.w);

    const int base = blockIdx.x * 160 + wid * 40;
    float bi = 0.0f, bd = 1.0f;                     // best (inter, denom): q=0
#pragma unroll 8
    for (int i = 0; i < 40; ++i) {
        float4 a = anc[base + i];                   // wave-uniform -> s_load
        float aarea = box_area(a.x, a.y, a.z, a.w);
        float inter, denom;
        inter_denom(g.x, g.y, g.z, g.w, garea, a.x, a.y, a.z, a.w, aarea,
                    inter, denom);
        if (frac_gt(inter, denom, bi, bd)) { bi = inter; bd = denom; }
    }

    __shared__ float pi[4][NG], pd[4][NG];
    pi[wid][lane] = bi;
    pd[wid][lane] = bd;
    __syncthreads();
    if (threadIdx.x < NG) {
        float ci = pi[0][threadIdx.x], cd = pd[0][threadIdx.x];
#pragma unroll
        for (int wv = 1; wv < 4; ++wv) {
            float ni = pi[wv][threadIdx.x], nd = pd[wv][threadIdx.x];
            if (frac_gt(ni, nd, ci, cd)) { ci = ni; cd = nd; }
        }
        float m = ci / cd;                          // single IEEE divide
        // IoU >= 0: float order == int order of bits
        atomicMax(reinterpret_cast<int*>(&highest[b * NG + threadIdx.x]),
                  __float_as_int(m));
    }
}

// --- kernel 2: per-anchor match + labels + matched boxes --------------------
// grid (625, NB), block 128; TWO anchors per thread (ai, ai+128) — halves
// per-g LDS issue slots and doubles independent divide chains. Rounded-value
// semantics require the per-pair IEEE divide here (argmax-first + eq vs hi).
__global__ __launch_bounds__(128) void k_assign(
        const float* __restrict__ anchors, const float* __restrict__ gts,
        const float* __restrict__ scores, const int* __restrict__ confs,
        const float* __restrict__ highest,
        float* __restrict__ labels_out, float4* __restrict__ boxes_out) {
    __shared__ float4 sg[NG];
    __shared__ float sga[NG], shi[NG], ssc[NG];
    __shared__ int scf[NG];

    const int b = blockIdx.y;
    if (threadIdx.x < NG) {
        const int gi = threadIdx.x;
        float4 gv = reinterpret_cast<const float4*>(gts)[b * NG + gi];
        sg[gi] = gv;
        sga[gi] = box_area(gv.x, gv.y, gv.z, gv.w);
        shi[gi] = highest[b * NG + gi];
        ssc[gi] = scores[b * NG + gi];
        scf[gi] = confs[b * NG + gi];
    }
    __syncthreads();

    const int ai0 = blockIdx.x * 256 + threadIdx.x;     // 0..159871
    const int ai1 = ai0 + 128;
    const float4* __restrict__ anc = reinterpret_cast<const float4*>(anchors) + (size_t)b * NA;
    float4 av0 = anc[ai0];
    float4 av1 = anc[ai1];
    float aarea0 = box_area(av0.x, av0.y, av0.z, av0.w);
    float aarea1 = box_area(av1.x, av1.y, av1.z, av1.w);

    float best0 = -1.0f, best1 = -1.0f;     // all-zero row -> argmax 0
    int   mat0 = 0, mat1 = 0;
    bool  lowq0 = false, lowq1 = false;
#pragma unroll
    for (int g = 0; g < NG; ++g) {
        float4 gb = sg[g];                              // LDS broadcast
        float ga = sga[g];
        float hg = shi[g];
        float v0 = iou_f(gb.x, gb.y, gb.z, gb.w, ga,
                         av0.x, av0.y, av0.z, av0.w, aarea0);
        float v1 = iou_f(gb.x, gb.y, gb.z, gb.w, ga,
                         av1.x, av1.y, av1.z, av1.w, aarea1);
        if (v0 > best0) { best0 = v0; mat0 = g; }       // strict > keeps FIRST
        if (v1 > best1) { best1 = v1; mat1 = g; }
        lowq0 |= (v0 == hg);                            // bit-exact equality
        lowq1 |= (v1 == hg);
    }

    const size_t obase = (size_t)b * NA;
#pragma unroll
    for (int k = 0; k < 2; ++k) {
        float best = k ? best1 : best0;
        int matches = k ? mat1 : mat0;
        bool lowq = k ? lowq1 : lowq0;
        int ai = k ? ai1 : ai0;

        int m    = (best < 0.3f) ? -1 : ((best < 0.7f) ? -2 : matches);
        int midx = lowq ? matches : m;
        int cl   = (midx < 0) ? 0 : midx;

        float4 mg = sg[cl];
        float  sc = ssc[cl];
        int    cf = scf[cl];

        bool pos = (midx >= 0);
        float lab = pos ? 1.0f : 0.0f;
        lab = fminf(lab, sc);
        if (midx == -1) lab = 0.0f;
        if (midx == -2) lab = -1.0f;
        if (sc < 1.0f && pos) lab = -1.0f;
        if (cf == 0 && pos) lab = -1.0f;

        labels_out[obase + ai] = lab;
        boxes_out[obase + ai] = mg;
    }
}

extern "C" void kernel_launch(void* const* d_in, const int* in_sizes, int n_in,
                              void* d_out, int out_size, void* d_ws, size_t ws_size,
                              hipStream_t stream) {
    const float* anchors = (const float*)d_in[0];   // [B,A,4]
    const float* gts     = (const float*)d_in[1];   // [B,G,4]
    const float* scores  = (const float*)d_in[2];   // [B,G]
    const int*   confs   = (const int*)d_in[3];     // [B,G]

    float* labels_out = (float*)d_out;                              // [B,A]
    float4* boxes_out = (float4*)((float*)d_out + (size_t)NB * NA); // [B,A,4]
    float* highest = (float*)d_ws;                                  // [B*G]

    hipMemsetAsync(d_ws, 0, (size_t)NB * NG * sizeof(float), stream);

    dim3 g1(1000, NB), g2(625, NB), blk1(256), blk2(128);
    k_gt_highest<<<g1, blk1, 0, stream>>>(anchors, gts, highest);
    k_assign<<<g2, blk2, 0, stream>>>(anchors, gts, scores, confs, highest,
                                      labels_out, boxes_out);
}

// Round 4
// 142.685 us; speedup vs baseline: 2.3178x; 1.0277x over previous
//
#include <hip/hip_runtime.h>

// Problem: B=4, A=160000 anchors, G=64 gt boxes.
// outputs (concat flat): labels [B,A] f32, matched_gt_boxes [B,A,4] f32
constexpr int NB = 4;
constexpr int NA = 160000;
constexpr int NG = 64;

// --- exact-rounding helpers -------------------------------------------------
// contract(off): stop fma fusion that would change rounding vs numpy.
__device__ __forceinline__ float box_area(float x0, float y0, float x1, float y1) {
#pragma clang fp contract(off)
    return (x1 - x0) * (y1 - y0);
}

// inter/denom with the exact op order of the numpy reference; shared by both
// kernels so phase-1's deferred quotient is bit-identical to phase-2's.
__device__ __forceinline__ void inter_denom(float gx0, float gy0, float gx1, float gy1, float garea,
                                            float ax0, float ay0, float ax1, float ay1, float aarea,
                                            float& inter, float& denom) {
#pragma clang fp contract(off)
    float ltx = fmaxf(gx0, ax0);
    float lty = fmaxf(gy0, ay0);
    float rbx = fminf(gx1, ax1);
    float rby = fminf(gy1, ay1);
    float w = fmaxf(rbx - ltx, 0.0f);
    float h = fmaxf(rby - lty, 0.0f);
    inter = w * h;
    float s = garea + aarea;        // numpy: area_gt + area_anchor
    denom = s - inter;
}

__device__ __forceinline__ float iou_f(float gx0, float gy0, float gx1, float gy1, float garea,
                                       float ax0, float ay0, float ax1, float ay1, float aarea) {
    float inter, denom;
    inter_denom(gx0, gy0, gx1, gy1, garea, ax0, ay0, ax1, ay1, aarea, inter, denom);
    return inter / denom;           // IEEE fp32 divide
}

// exact comparison  i1/d1 > i2/d2  (all >= 0, d > 0): f64 products of fp32
// are exact (24x24 bits <= 53), so this is the REAL-number ordering. Rounding
// is monotone, so the real-max pair's fp32 quotient == max of rounded quotients.
__device__ __forceinline__ bool frac_gt(float i1, float d1, float i2, float d2) {
    return (double)i1 * (double)d2 > (double)i2 * (double)d1;
}

// --- kernel 1: highest IoU per gt (unchanged from round 3) ------------------
__global__ __launch_bounds__(256) void k_gt_highest(
        const float* __restrict__ anchors, const float* __restrict__ gts,
        float* __restrict__ highest /* [B*G], pre-zeroed */) {
    const int b = blockIdx.y;
    const int lane = threadIdx.x & 63;
    const int wid = __builtin_amdgcn_readfirstlane(threadIdx.x >> 6);

    const float4* __restrict__ gt4 = reinterpret_cast<const float4*>(gts) + b * NG;
    const float4* __restrict__ anc = reinterpret_cast<const float4*>(anchors) + (size_t)b * NA;

    float4 g = gt4[lane];
    float garea = box_area(g.x, g.y, g.z, g.w);

    const int base = blockIdx.x * 160 + wid * 40;
    float bi = 0.0f, bd = 1.0f;                     // best (inter, denom): q=0
#pragma unroll 8
    for (int i = 0; i < 40; ++i) {
        float4 a = anc[base + i];                   // wave-uniform -> s_load
        float aarea = box_area(a.x, a.y, a.z, a.w);
        float inter, denom;
        inter_denom(g.x, g.y, g.z, g.w, garea, a.x, a.y, a.z, a.w, aarea,
                    inter, denom);
        if (frac_gt(inter, denom, bi, bd)) { bi = inter; bd = denom; }
    }

    __shared__ float pi[4][NG], pd[4][NG];
    pi[wid][lane] = bi;
    pd[wid][lane] = bd;
    __syncthreads();
    if (threadIdx.x < NG) {
        float ci = pi[0][threadIdx.x], cd = pd[0][threadIdx.x];
#pragma unroll
        for (int wv = 1; wv < 4; ++wv) {
            float ni = pi[wv][threadIdx.x], nd = pd[wv][threadIdx.x];
            if (frac_gt(ni, nd, ci, cd)) { ci = ni; cd = nd; }
        }
        float m = ci / cd;                          // single IEEE divide
        atomicMax(reinterpret_cast<int*>(&highest[b * NG + threadIdx.x]),
                  __float_as_int(m));
    }
}

// --- kernel 2: per-anchor match + labels + matched boxes --------------------
// grid (625, NB), block 256, ONE anchor per thread. Inner-loop gt data packed
// into two LDS reads per g (b128 box + b64 {area,hi}); unroll BOUNDED at 4 so
// register pressure stays low (R2/R3's full 64-way unroll spilled: 64 hoisted
// LDS loads + div_scale/fmas/fixup temporaries).
__global__ __launch_bounds__(256) void k_assign(
        const float* __restrict__ anchors, const float* __restrict__ gts,
        const float* __restrict__ scores, const int* __restrict__ confs,
        const float* __restrict__ highest,
        float* __restrict__ labels_out, float4* __restrict__ boxes_out) {
    __shared__ float4 sg[NG];       // gt box
    __shared__ float2 sah[NG];      // {garea, highest}
    __shared__ float ssc[NG];
    __shared__ int scf[NG];

    const int b = blockIdx.y;
    if (threadIdx.x < NG) {
        const int gi = threadIdx.x;
        float4 gv = reinterpret_cast<const float4*>(gts)[b * NG + gi];
        sg[gi] = gv;
        sah[gi] = make_float2(box_area(gv.x, gv.y, gv.z, gv.w),
                              highest[b * NG + gi]);
        ssc[gi] = scores[b * NG + gi];
        scf[gi] = confs[b * NG + gi];
    }
    __syncthreads();

    const int ai = blockIdx.x * 256 + threadIdx.x;  // 0..159999
    const float4* __restrict__ anc = reinterpret_cast<const float4*>(anchors) + (size_t)b * NA;
    float4 av = anc[ai];
    float aarea = box_area(av.x, av.y, av.z, av.w);

    float best = -1.0f;             // all-zero row -> argmax 0 (first max)
    int   matches = 0;
    bool  lowq = false;
#pragma unroll 4
    for (int g = 0; g < NG; ++g) {
        float4 gb = sg[g];                          // ds_read_b128 broadcast
        float2 ah = sah[g];                         // ds_read_b64 broadcast
        float v = iou_f(gb.x, gb.y, gb.z, gb.w, ah.x,
                        av.x, av.y, av.z, av.w, aarea);
        if (v > best) { best = v; matches = g; }    // strict > keeps FIRST max
        lowq |= (v == ah.y);                        // bit-exact equality
    }

    int m    = (best < 0.3f) ? -1 : ((best < 0.7f) ? -2 : matches);
    int midx = lowq ? matches : m;
    int cl   = (midx < 0) ? 0 : midx;

    float4 mg = sg[cl];
    float  sc = ssc[cl];
    int    cf = scf[cl];

    bool pos = (midx >= 0);
    float lab = pos ? 1.0f : 0.0f;
    lab = fminf(lab, sc);
    if (midx == -1) lab = 0.0f;
    if (midx == -2) lab = -1.0f;
    if (sc < 1.0f && pos) lab = -1.0f;
    if (cf == 0 && pos) lab = -1.0f;

    labels_out[(size_t)b * NA + ai] = lab;
    boxes_out[(size_t)b * NA + ai] = mg;
}

extern "C" void kernel_launch(void* const* d_in, const int* in_sizes, int n_in,
                              void* d_out, int out_size, void* d_ws, size_t ws_size,
                              hipStream_t stream) {
    const float* anchors = (const float*)d_in[0];   // [B,A,4]
    const float* gts     = (const float*)d_in[1];   // [B,G,4]
    const float* scores  = (const float*)d_in[2];   // [B,G]
    const int*   confs   = (const int*)d_in[3];     // [B,G]

    float* labels_out = (float*)d_out;                              // [B,A]
    float4* boxes_out = (float4*)((float*)d_out + (size_t)NB * NA); // [B,A,4]
    float* highest = (float*)d_ws;                                  // [B*G]

    hipMemsetAsync(d_ws, 0, (size_t)NB * NG * sizeof(float), stream);

    dim3 g1(1000, NB), g2(625, NB), blk(256);
    k_gt_highest<<<g1, blk, 0, stream>>>(anchors, gts, highest);
    k_assign<<<g2, blk, 0, stream>>>(anchors, gts, scores, confs, highest,
                                     labels_out, boxes_out);
}